// Round 1
// baseline (467.613 us; speedup 1.0000x reference)
//
#include <hip/hip_runtime.h>

// 2-layer LSTM, B=1024 T=512 D=1 H=64.
// 512 blocks x 256 threads (4 waves), MB=2 batches per block -> 2 independent
// blocks (barrier domains) per CU so their stalls decorrelate.
// Each wave owns 16 hidden units for BOTH layers: layer0 at step t and layer1
// at step t-1 (software pipeline), 8+16=24 MFMAs/wave, balanced at the barrier.
// Layer1 reuses layer0's h0 A-fragments (4 ds_read_b128 per wave-step).
// MFMA M=16 with rows 2-15 unused (zero). Post-MFMA: gates live in quad-0
// lanes regs 0-1; redistribute via 16 ds_bpermute (__shfl) so each lane does
// exactly 1 lstm_point: lane -> (layer=quad>>1, batch=quad&1, unit=(w<<4)|c).
// One __syncthreads per step; h tiles XOR-swizzled, parity double-buffered.
// x staged double-buffered mid-chunk (no extra barriers).

typedef _Float16 f16x8 __attribute__((ext_vector_type(8)));
typedef float f32x4 __attribute__((ext_vector_type(4)));

#define TSTEPS 512
#define L2E 1.44269504088896340736f

__device__ __forceinline__ int hidx(int row, int j) {
    // swizzled index into a 16x64 half tile
    return row * 64 + ((((j >> 3) ^ (row & 7)) << 3) | (j & 7));
}

__device__ __forceinline__ float lstm_point(float ai, float af, float ag, float ao,
                                            float& c) {
    // ai,af,ao pre-scaled by -log2e ; ag by +2log2e
    const float p  = __builtin_amdgcn_exp2f(ai);
    const float s_ = __builtin_amdgcn_exp2f(af);
    const float r_ = __builtin_amdgcn_exp2f(ag);
    const float v  = __builtin_amdgcn_exp2f(ao);
    const float f  = __builtin_amdgcn_rcpf(1.f + s_);
    const float ig = (r_ - 1.f) * __builtin_amdgcn_rcpf((1.f + p) * (1.f + r_));
    const float cc = __builtin_fmaf(f, c, ig);
    c = cc;
    const float w  = __builtin_amdgcn_exp2f(cc * (2.f * L2E));
    return (w - 1.f) * __builtin_amdgcn_rcpf((1.f + v) * (1.f + w));
}

__global__ __launch_bounds__(256, 2) void lstm2_kernel(
    const float* __restrict__ x,
    const float* __restrict__ W_ih0, const float* __restrict__ W_hh0,
    const float* __restrict__ b_ih0, const float* __restrict__ b_hh0,
    const float* __restrict__ W_ih1, const float* __restrict__ W_hh1,
    const float* __restrict__ b_ih1, const float* __restrict__ b_hh1,
    const float* __restrict__ W_fc,  const float* __restrict__ b_fc,
    float* __restrict__ out)
{
    __shared__ _Float16 hs[4][16 * 64];   // [0..1] = h0 parity 0/1, [2..3] = h1 parity 0/1
    __shared__ float    xlds[2][64 * 2];  // double-buffered x chunks: [buf][step*2 + m]

    const int tid  = (int)threadIdx.x;
    const int lane = tid & 63;
    const int w    = tid >> 6;          // wave 0..3: units w*16 .. w*16+15
    const int c    = lane & 15;
    const int quad = lane >> 4;
    const int L    = quad >> 1;         // this lane's point: layer 0/1
    const int m    = quad & 1;          //                    batch 0/1
    const int j    = (w << 4) | c;      //                    hidden unit
    const int b0   = (int)blockIdx.x * 2;

    const int rdA0 = hidx(c, quad * 8);
    const int rdA1 = hidx(c, quad * 8 + 32);
    const int wrH  = hidx(m, j);

    // ---- per-wave register weight fragments for BOTH layers ----
    float biasc0[4], wih0c[4], biasc1[4];
    f16x8 bf0[4][2];   // W_hh0, K=64 in 2 chunks
    f16x8 bf1[4][4];   // [W_ih1 | W_hh1], K=128 in 4 chunks

#pragma unroll
    for (int g = 0; g < 4; ++g) {
        const int n = j + 64 * g;
        const float sg = (g == 2) ? (2.0f * L2E) : (-L2E);
        biasc0[g] = sg * (b_ih0[n] + b_hh0[n]);
        wih0c[g]  = sg * W_ih0[n];                 // D == 1
        biasc1[g] = sg * (b_ih1[n] + b_hh1[n]);
#pragma unroll
        for (int kb = 0; kb < 2; ++kb) {
            const float* p = W_hh0 + n * 64 + kb * 32 + quad * 8;
#pragma unroll
            for (int q = 0; q < 8; ++q) bf0[g][kb][q] = (_Float16)(p[q] * sg);
        }
#pragma unroll
        for (int kb = 0; kb < 4; ++kb) {
            const int kk = kb * 32 + quad * 8;
            const float* p = (kk < 64) ? (W_ih1 + n * 64 + kk)
                                       : (W_hh1 + n * 64 + (kk - 64));
#pragma unroll
            for (int q = 0; q < 8; ++q) bf1[g][kb][q] = (_Float16)(p[q] * sg);
        }
    }

    // zero-init h buffers (rows 2-15 stay zero forever) + stage x chunk 0
    for (int i = tid; i < 4 * 16 * 64; i += 256) ((_Float16*)hs)[i] = (_Float16)0.f;
    if (tid < 128) {
        const int i = tid >> 1, mm = tid & 1;
        xlds[0][i * 2 + mm] = x[(b0 + mm) * TSTEPS + i];
    }
    __syncthreads();

    float cst = 0.f;           // cell state for this lane's (L, m, j)
    const f32x4 zf4 = {0.f, 0.f, 0.f, 0.f};

    for (int t = 0; t <= TSTEPS; ++t) {
        const int pr  = (t + 1) & 1;   // parity of h0(t-1) — read by L0 AND L1
        const int pr1 = t & 1;         // parity of h1(t-2) — read by L1

        // stage next x chunk mid-chunk into the other buffer (no extra barrier:
        // first read of chunk cn is ~32 barriers later)
        if ((t & 63) == 32 && (t >> 6) < 7) {
            if (tid < 128) {
                const int i = tid >> 1, mm = tid & 1;
                const int cn = (t >> 6) + 1;
                xlds[cn & 1][i * 2 + mm] = x[(b0 + mm) * TSTEPS + cn * 64 + i];
            }
        }

        const f16x8 a0 = *(const f16x8*)&hs[pr][rdA0];        // h0(t-1) k 0..31
        const f16x8 a1 = *(const f16x8*)&hs[pr][rdA1];        // h0(t-1) k 32..63
        const f16x8 a2 = *(const f16x8*)&hs[2 + pr1][rdA0];   // h1(t-2) k 0..31
        const f16x8 a3 = *(const f16x8*)&hs[2 + pr1][rdA1];   // h1(t-2) k 32..63

        const float xv0 = xlds[(t >> 6) & 1][(t & 63) * 2 + 0];
        const float xv1 = xlds[(t >> 6) & 1][(t & 63) * 2 + 1];

        f32x4 p0[4], q0[4], p1[4], q1[4];
#pragma unroll
        for (int g = 0; g < 4; ++g) {
            f32x4 ini;
            ini[0] = __builtin_fmaf(xv0, wih0c[g], biasc0[g]);
            ini[1] = __builtin_fmaf(xv1, wih0c[g], biasc0[g]);
            ini[2] = biasc0[g]; ini[3] = biasc0[g];
            // layer0, step t (split accumulator)
            p0[g] = __builtin_amdgcn_mfma_f32_16x16x32_f16(a0, bf0[g][0], ini, 0, 0, 0);
            q0[g] = __builtin_amdgcn_mfma_f32_16x16x32_f16(a1, bf0[g][1], zf4, 0, 0, 0);
            // layer1, step t-1 (reuses a0,a1 = h0(t-1); split accumulator)
            const f32x4 ini1 = {biasc1[g], biasc1[g], biasc1[g], biasc1[g]};
            f32x4 acc = __builtin_amdgcn_mfma_f32_16x16x32_f16(a0, bf1[g][0], ini1, 0, 0, 0);
            acc       = __builtin_amdgcn_mfma_f32_16x16x32_f16(a1, bf1[g][1], acc,  0, 0, 0);
            p1[g] = acc;
            f32x4 acq = __builtin_amdgcn_mfma_f32_16x16x32_f16(a2, bf1[g][2], zf4, 0, 0, 0);
            acq       = __builtin_amdgcn_mfma_f32_16x16x32_f16(a3, bf1[g][3], acq, 0, 0, 0);
            q1[g] = acq;
        }

        // redistribute: C rows 0-1 (batches) live in quad-0 lanes' regs 0-1
        float gate[4];
#pragma unroll
        for (int g = 0; g < 4; ++g) {
            const float u00 = p0[g][0] + q0[g][0];   // L0 batch0, unit c (valid in quad0)
            const float u01 = p0[g][1] + q0[g][1];   // L0 batch1
            const float u10 = p1[g][0] + q1[g][0];   // L1 batch0
            const float u11 = p1[g][1] + q1[g][1];   // L1 batch1
            const float g00 = __shfl(u00, c, 64);
            const float g01 = __shfl(u01, c, 64);
            const float g10 = __shfl(u10, c, 64);
            const float g11 = __shfl(u11, c, 64);
            const float gl0 = m ? g01 : g00;
            const float gl1 = m ? g11 : g10;
            gate[g] = L ? gl1 : gl0;
        }

        // L0 computes h0(t) valid for t<512; L1 computes h1(t-1) valid for t>0
        const bool active = L ? (t > 0) : (t < TSTEPS);
        if (active) {
            const float hv = lstm_point(gate[0], gate[1], gate[2], gate[3], cst);
            const int par = (t & 1) ^ L;      // L0 -> t&1 ; L1 -> (t-1)&1
            hs[L * 2 + par][wrH] = (_Float16)hv;
        }
        __syncthreads();
    }

    // ---- epilogue: h0(511) in hs[1], h1(511) in hs[3] ----
    if (tid < 4) {
        const int which = tid >> 1, mm = tid & 1;
        const _Float16* hb = &hs[which * 2 + 1][0];
        float s = b_fc[0];
        for (int jj = 0; jj < 64; ++jj) s += (float)hb[hidx(mm, jj)] * W_fc[jj];
        out[which * 1024 + b0 + mm] = s;
    }
}

extern "C" void kernel_launch(void* const* d_in, const int* in_sizes, int n_in,
                              void* d_out, int out_size, void* d_ws, size_t ws_size,
                              hipStream_t stream) {
    (void)in_sizes; (void)n_in; (void)d_ws; (void)ws_size; (void)out_size;
    lstm2_kernel<<<512, 256, 0, stream>>>(
        (const float*)d_in[0],
        (const float*)d_in[1], (const float*)d_in[2],
        (const float*)d_in[3], (const float*)d_in[4],
        (const float*)d_in[5], (const float*)d_in[6],
        (const float*)d_in[7], (const float*)d_in[8],
        (const float*)d_in[9], (const float*)d_in[10],
        (float*)d_out);
}

// Round 2
// 435.725 us; speedup vs baseline: 1.0732x; 1.0732x over previous
//
#include <hip/hip_runtime.h>

// 2-layer LSTM, B=1024 T=512 D=1 H=64. 128 blocks x 256 threads (4 waves), MB=8.
// Row-split trick: L0 occupies C rows 0-7, L1 rows 8-15 of the same M=16 MFMA
// tile. A fragment = h[c&7][k] (rows 8-15 duplicate batches 0-7), so L1's
// results land in quads 2-3 while L0's land in quads 0-1. Every lane gets its
// 4 lstm_points (layer=quad>>1, batches (quad&1)*4+r, unit=w*16+c) from its
// OWN accumulator registers: ZERO cross-lane shuffles.
// A-frags shared between layers (4 ds_read_b128/step). MFMA chains fully
// accumulated (no split+add). One __syncthreads per step; h tiles [8][64] f16
// XOR-swizzled, parity double-buffered; x staged in LDS, double-buffered.

typedef _Float16 f16x8 __attribute__((ext_vector_type(8)));
typedef float f32x4 __attribute__((ext_vector_type(4)));

#define TSTEPS 512
#define L2E 1.44269504088896340736f

__device__ __forceinline__ float lstm_point(float ai, float af, float ag, float ao,
                                            float& c) {
    // ai,af,ao pre-scaled by -log2e ; ag by +2log2e
    const float p  = __builtin_amdgcn_exp2f(ai);
    const float s_ = __builtin_amdgcn_exp2f(af);
    const float r_ = __builtin_amdgcn_exp2f(ag);
    const float v  = __builtin_amdgcn_exp2f(ao);
    const float f  = __builtin_amdgcn_rcpf(1.f + s_);
    const float ig = (r_ - 1.f) * __builtin_amdgcn_rcpf((1.f + p) * (1.f + r_));
    const float cc = __builtin_fmaf(f, c, ig);
    c = cc;
    const float w  = __builtin_amdgcn_exp2f(cc * (2.f * L2E));
    return (w - 1.f) * __builtin_amdgcn_rcpf((1.f + v) * (1.f + w));
}

__global__ __launch_bounds__(256, 1) void lstm2_kernel(
    const float* __restrict__ x,
    const float* __restrict__ W_ih0, const float* __restrict__ W_hh0,
    const float* __restrict__ b_ih0, const float* __restrict__ b_hh0,
    const float* __restrict__ W_ih1, const float* __restrict__ W_hh1,
    const float* __restrict__ b_ih1, const float* __restrict__ b_hh1,
    const float* __restrict__ W_fc,  const float* __restrict__ b_fc,
    float* __restrict__ out)
{
    // h tiles: [parity][8 batches][64 units] f16, XOR-swizzled within rows.
    __shared__ alignas(16) _Float16 h0s[2 * 512];
    __shared__ alignas(16) _Float16 h1s[2 * 512];
    __shared__ alignas(16) float    xl[2 * 512];   // [buf][step-in-chunk][8 batches]

    const int tid  = (int)threadIdx.x;
    const int lane = tid & 63;
    const int w    = tid >> 6;          // wave 0..3: units w*16 .. w*16+15
    const int c    = lane & 15;
    const int quad = lane >> 4;
    const int L    = quad >> 1;         // this lane's layer (0/1)
    const int qb   = quad & 1;          // batch half (0: b0-3, 1: b4-7)
    const int j    = (w << 4) | c;      // hidden unit owned by this lane
    const int b0   = (int)blockIdx.x * 8;
    const int r8   = c & 7;

    // A-frag read offsets (bytes, within one parity tile):
    // element (row=c&7, k=quad*8+q) -> grp=quad (a0) / quad+4 (a1), slot=(grp^row)&7
    const int rdOff0 = r8 * 128 + (((quad    ) ^ r8) & 7) * 16;
    const int rdOff1 = r8 * 128 + (((quad + 4) ^ r8) & 7) * 16;
    // h write offsets (bytes) for the lane's 4 points: (batch=qb*4+r, unit=j)
    const int grp = (w << 1) | (c >> 3);   // = j>>3
    int wOff[4];
#pragma unroll
    for (int r = 0; r < 4; ++r) {
        const int b = qb * 4 + r;
        wOff[r] = b * 128 + ((grp ^ b) & 7) * 16 + (c & 7) * 2;
    }

    // ---- per-lane weight fragments for BOTH layers ----
    float biasc0[4], wih0c[4];
    f32x4 cini1[4];               // layer1 C-in = splat of scaled bias
    f16x8 bf0[4][2];              // W_hh0, K=64 in 2 chunks
    f16x8 bf1[4][4];              // [W_ih1 | W_hh1], K=128 in 4 chunks

#pragma unroll
    for (int g = 0; g < 4; ++g) {
        const int n = j + 64 * g;
        const float sg = (g == 2) ? (2.0f * L2E) : (-L2E);
        biasc0[g] = sg * (b_ih0[n] + b_hh0[n]);
        wih0c[g]  = sg * W_ih0[n];                 // D == 1
        const float bb1 = sg * (b_ih1[n] + b_hh1[n]);
        cini1[g][0] = bb1; cini1[g][1] = bb1; cini1[g][2] = bb1; cini1[g][3] = bb1;
#pragma unroll
        for (int kb = 0; kb < 2; ++kb) {
            const float* p = W_hh0 + n * 64 + kb * 32 + quad * 8;
#pragma unroll
            for (int q = 0; q < 8; ++q) bf0[g][kb][q] = (_Float16)(p[q] * sg);
        }
#pragma unroll
        for (int kb = 0; kb < 4; ++kb) {
            const int kk = kb * 32 + quad * 8;
            const float* p = (kk < 64) ? (W_ih1 + n * 64 + kk)
                                       : (W_hh1 + n * 64 + (kk - 64));
#pragma unroll
            for (int q = 0; q < 8; ++q) bf1[g][kb][q] = (_Float16)(p[q] * sg);
        }
    }

    // zero-init h tiles (both parities) + stage x chunk 0
    for (int i = tid; i < 1024; i += 256) { h0s[i] = (_Float16)0.f; h1s[i] = (_Float16)0.f; }
    for (int k2 = tid; k2 < 512; k2 += 256) {
        const int i = k2 >> 3, m = k2 & 7;
        xl[i * 8 + m] = x[(b0 + m) * TSTEPS + i];
    }
    __syncthreads();

    float cst[4] = {0.f, 0.f, 0.f, 0.f};   // cell states for the lane's 4 points

    for (int t = 0; t <= TSTEPS; ++t) {
        // stage next x chunk mid-chunk into the other buffer
        if ((t & 63) == 32 && (t >> 6) < 7) {
            const int cn = (t >> 6) + 1;
            const int bufo = (cn & 1) * 512;
            for (int k2 = tid; k2 < 512; k2 += 256) {
                const int i = k2 >> 3, m = k2 & 7;
                xl[bufo + i * 8 + m] = x[(b0 + m) * TSTEPS + cn * 64 + i];
            }
        }

        const int pr  = (t + 1) & 1;   // parity of h0(t-1) (read by L0 and L1)
        const int pr1 = t & 1;         // parity of h1(t-2) (read) and h0(t) (write)

        const f16x8 a0 = *(const f16x8*)((const char*)h0s + pr  * 1024 + rdOff0);
        const f16x8 a1 = *(const f16x8*)((const char*)h0s + pr  * 1024 + rdOff1);
        const f16x8 a2 = *(const f16x8*)((const char*)h1s + pr1 * 1024 + rdOff0);
        const f16x8 a3 = *(const f16x8*)((const char*)h1s + pr1 * 1024 + rdOff1);
        const f32x4 xv = *(const f32x4*)((const char*)xl + ((t >> 6) & 1) * 2048
                                         + (t & 63) * 32 + qb * 16);

        f32x4 acc0[4], acc1[4];
#pragma unroll
        for (int g = 0; g < 4; ++g) {
            f32x4 ini;
#pragma unroll
            for (int r = 0; r < 4; ++r) ini[r] = __builtin_fmaf(xv[r], wih0c[g], biasc0[g]);
            // layer0, step t: rows 0-7 valid
            f32x4 A = __builtin_amdgcn_mfma_f32_16x16x32_f16(a0, bf0[g][0], ini, 0, 0, 0);
            A       = __builtin_amdgcn_mfma_f32_16x16x32_f16(a1, bf0[g][1], A,   0, 0, 0);
            acc0[g] = A;
            // layer1, step t-1: rows 8-15 valid (A rows 8-15 duplicate batches 0-7)
            f32x4 Bq = __builtin_amdgcn_mfma_f32_16x16x32_f16(a0, bf1[g][0], cini1[g], 0, 0, 0);
            Bq       = __builtin_amdgcn_mfma_f32_16x16x32_f16(a1, bf1[g][1], Bq, 0, 0, 0);
            Bq       = __builtin_amdgcn_mfma_f32_16x16x32_f16(a2, bf1[g][2], Bq, 0, 0, 0);
            Bq       = __builtin_amdgcn_mfma_f32_16x16x32_f16(a3, bf1[g][3], Bq, 0, 0, 0);
            acc1[g] = Bq;
        }

        // L0 computes h0(t), valid t<512; L1 computes h1(t-1), valid t>0
        const bool active = L ? (t > 0) : (t < TSTEPS);
        if (active) {
            char* wbase = L ? ((char*)h1s + pr * 1024) : ((char*)h0s + pr1 * 1024);
#pragma unroll
            for (int r = 0; r < 4; ++r) {
                const float g0 = L ? acc1[0][r] : acc0[0][r];
                const float g1 = L ? acc1[1][r] : acc0[1][r];
                const float g2 = L ? acc1[2][r] : acc0[2][r];
                const float g3 = L ? acc1[3][r] : acc0[3][r];
                const float hv = lstm_point(g0, g1, g2, g3, cst[r]);
                *(_Float16*)(wbase + wOff[r]) = (_Float16)hv;
            }
        }
        __syncthreads();
    }

    // ---- epilogue: h0(511) and h1(511) both in parity-1 tiles ----
    if (tid < 16) {
        const int which = tid >> 3, b = tid & 7;
        const _Float16* hb = which ? &h1s[512] : &h0s[512];
        float s = b_fc[0];
        for (int jj = 0; jj < 64; ++jj) {
            const int off = b * 64 + (((jj >> 3) ^ b) & 7) * 8 + (jj & 7);
            s += (float)hb[off] * W_fc[jj];
        }
        out[which * 1024 + b0 + b] = s;
    }
}

extern "C" void kernel_launch(void* const* d_in, const int* in_sizes, int n_in,
                              void* d_out, int out_size, void* d_ws, size_t ws_size,
                              hipStream_t stream) {
    (void)in_sizes; (void)n_in; (void)d_ws; (void)ws_size; (void)out_size;
    lstm2_kernel<<<128, 256, 0, stream>>>(
        (const float*)d_in[0],
        (const float*)d_in[1], (const float*)d_in[2],
        (const float*)d_in[3], (const float*)d_in[4],
        (const float*)d_in[5], (const float*)d_in[6],
        (const float*)d_in[7], (const float*)d_in[8],
        (const float*)d_in[9], (const float*)d_in[10],
        (float*)d_out);
}